// Round 3
// baseline (1108.116 us; speedup 1.0000x reference)
//
#include <hip/hip_runtime.h>
#include <hip/hip_bf16.h>

// GRU, 16 steps, B=4096, H=1024. x==h for steps>=1 -> combined gate weights.
// Gate GEMM (fused): Z = h_bf16 @ Wc'[4H,H]^T, gate-interleaved so the MFMA
//   epilogue holds all 4 gates of one h-col per thread -> h_new in-register.
//   h state kept in bf16 only (ping-pong hbA/hbB).
// Out GEMM: batched over all 16 steps (M=65536, N=1024, K=1024).
// Both GEMMs: XCD-chunked blockIdx swizzle (T1) for L2 A-panel reuse.

#define H_DIM 1024
#define BATCH_N 4096
#define NSTEPS 16
#define K4 (4 * H_DIM)

typedef __bf16 bf16_t;
typedef __bf16 bf16x8 __attribute__((ext_vector_type(8)));
typedef float f32x4 __attribute__((ext_vector_type(4)));

__device__ __forceinline__ float sigm(float x) { return 1.0f / (1.0f + __expf(-x)); }

// ---------------- prep kernels ----------------
// Wc' row c' (0..4095): gate g=(c'>>4)&3, h-row hc=((c'>>6)<<4)|(c'&15)
//   g: 0=r (Wih+Whh), 1=z (Wih+Whh), 2=i_n (Wih), 3=h_n (Whh)

__global__ __launch_bounds__(256) void prep_weights(
    const float* __restrict__ Wih, const float* __restrict__ Whh,
    const float* __restrict__ bih, const float* __restrict__ bhh,
    const float* __restrict__ Wout,
    bf16_t* __restrict__ Wc0, bf16_t* __restrict__ Wc,
    bf16_t* __restrict__ Wob, float* __restrict__ biasc)
{
    const int stride = gridDim.x * blockDim.x;
    const int idx = blockIdx.x * blockDim.x + threadIdx.x;

    const int total = K4 * H_DIM;
    for (int i = idx; i < total; i += stride) {
        const int c2 = i >> 10;            // permuted row
        const int col = i & (H_DIM - 1);
        const int gate = (c2 >> 4) & 3;
        const int hc = ((c2 >> 6) << 4) | (c2 & 15);
        float vc, v0;
        if (gate == 0) {
            float a = Wih[(size_t)hc * H_DIM + col];
            float b = Whh[(size_t)hc * H_DIM + col];
            vc = a + b; v0 = b;
        } else if (gate == 1) {
            float a = Wih[(size_t)(H_DIM + hc) * H_DIM + col];
            float b = Whh[(size_t)(H_DIM + hc) * H_DIM + col];
            vc = a + b; v0 = b;
        } else if (gate == 2) {
            vc = Wih[(size_t)(2 * H_DIM + hc) * H_DIM + col];
            v0 = 0.0f;   // step 0: x = 0
        } else {
            float b = Whh[(size_t)(2 * H_DIM + hc) * H_DIM + col];
            vc = b; v0 = b;
        }
        Wc[i]  = (bf16_t)vc;
        Wc0[i] = (bf16_t)v0;
    }
    for (int i = idx; i < H_DIM * H_DIM; i += stride)
        Wob[i] = (bf16_t)Wout[i];
    // biasc gate-major [4][H]
    for (int i = idx; i < K4; i += stride) {
        const int gate = i >> 10;
        const int hc = i & (H_DIM - 1);
        float v;
        if (gate == 0)      v = bih[hc] + bhh[hc];
        else if (gate == 1) v = bih[H_DIM + hc] + bhh[H_DIM + hc];
        else if (gate == 2) v = bih[2 * H_DIM + hc];
        else                v = bhh[2 * H_DIM + hc];
        biasc[i] = v;
    }
}

__global__ __launch_bounds__(256) void prep_h(
    const float* __restrict__ h0, bf16_t* __restrict__ hb)
{
    const int stride = gridDim.x * blockDim.x;
    for (int i = blockIdx.x * blockDim.x + threadIdx.x; i < BATCH_N * H_DIM; i += stride)
        hb[i] = (bf16_t)h0[i];
}

// ---------------- GEMM: 128x128 tile, BK=64, 4 waves, global_load_lds ----------------
// FUSED=1: gate GEMM + GRU epilogue (N must be 4096, gate-interleaved B).
// FUSED=0: C[M,N] = A@Bm^T + bias.
// Both: XCD-chunked blockIdx swizzle (nwg must be multiple of 8).

template <bool FUSED>
__global__ __launch_bounds__(256, 2) void gemm_bt(
    const bf16_t* __restrict__ A, const bf16_t* __restrict__ Bm,
    int M, int N, int K,
    float* __restrict__ C, const float* __restrict__ bias,
    const float* __restrict__ biasc,
    bf16_t* __restrict__ hbout, bf16_t* __restrict__ hr)
{
    __shared__ bf16_t la[128 * 64];
    __shared__ bf16_t lb[128 * 64];

    const int tid = threadIdx.x;
    const int l = tid & 63;
    const int w = tid >> 6;

    // T1: XCD-chunked swizzle. dispatch idx d -> XCD d%8; give XCD x the
    // contiguous logical chunk [x*cpx, (x+1)*cpx).
    const int nwg = gridDim.x * gridDim.y;
    const int cpx = nwg >> 3;
    int bid = blockIdx.y * gridDim.x + blockIdx.x;
    bid = (bid & 7) * cpx + (bid >> 3);
    const int bx = bid % gridDim.x;
    const int by = bid / gridDim.x;
    const int brow = by * 128;
    const int bcol = bx * 128;
    const int wr = w >> 1, wc = w & 1;

    f32x4 acc[4][4];
    const f32x4 zero = {0.f, 0.f, 0.f, 0.f};
#pragma unroll
    for (int m = 0; m < 4; ++m)
#pragma unroll
        for (int n = 0; n < 4; ++n) acc[m][n] = zero;

    const int lrow = l >> 3;
    const int lcol = (l & 7) * 8;

    const int nk = K >> 6;
    for (int kt = 0; kt < nk; ++kt) {
        __syncthreads();
        const int k0 = kt * 64;
#pragma unroll
        for (int i = 0; i < 4; ++i) {
            const int chunk = w * 32 + i * 8;
            const bf16_t* ga = A + (size_t)(brow + chunk + lrow) * K + k0 + lcol;
            const bf16_t* gb = Bm + (size_t)(bcol + chunk + lrow) * K + k0 + lcol;
            __builtin_amdgcn_global_load_lds(
                (const __attribute__((address_space(1))) void*)ga,
                (__attribute__((address_space(3))) void*)(la + chunk * 64), 16, 0, 0);
            __builtin_amdgcn_global_load_lds(
                (const __attribute__((address_space(1))) void*)gb,
                (__attribute__((address_space(3))) void*)(lb + chunk * 64), 16, 0, 0);
        }
        __syncthreads();

#pragma unroll
        for (int kk = 0; kk < 2; ++kk) {
            bf16x8 af[4], bfr[4];
#pragma unroll
            for (int m = 0; m < 4; ++m)
                af[m] = *(const bf16x8*)&la[(wr * 64 + m * 16 + (l & 15)) * 64 + kk * 32 + (l >> 4) * 8];
#pragma unroll
            for (int n = 0; n < 4; ++n)
                bfr[n] = *(const bf16x8*)&lb[(wc * 64 + n * 16 + (l & 15)) * 64 + kk * 32 + (l >> 4) * 8];
#pragma unroll
            for (int m = 0; m < 4; ++m)
#pragma unroll
                for (int n = 0; n < 4; ++n)
                    acc[m][n] = __builtin_amdgcn_mfma_f32_16x16x32_bf16(af[m], bfr[n], acc[m][n], 0, 0, 0);
        }
    }

    // C/D layout: col = lane&15, row = (lane>>4)*4 + j  [verified m89/m91]
    if constexpr (FUSED) {
        // thread holds gates g=n (r,z,i_n,h_n) of h-col hc
        const int hc = (bcol >> 2) + wc * 16 + (l & 15);
        const float br_ = biasc[hc];
        const float bz_ = biasc[H_DIM + hc];
        const float bi_ = biasc[2 * H_DIM + hc];
        const float bh_ = biasc[3 * H_DIM + hc];
        const int r0 = brow + wr * 64 + ((l >> 4) << 2);
#pragma unroll
        for (int m = 0; m < 4; ++m) {
#pragma unroll
            for (int j = 0; j < 4; ++j) {
                const int row = r0 + m * 16 + j;
                const size_t o = (size_t)row * H_DIM + hc;
                const float hold = (float)A[o];   // h_old from bf16 state (read-only this launch)
                const float r = sigm(acc[m][0][j] + br_);
                const float z = sigm(acc[m][1][j] + bz_);
                float a = acc[m][2][j] + bi_ + r * (acc[m][3][j] + bh_);
                a = fminf(fmaxf(a, -30.f), 30.f);
                const float e = __expf(-2.f * a);
                const float n = (1.f - e) / (1.f + e);
                const float hn = (1.f - z) * n + z * hold;
                hbout[o] = (bf16_t)hn;
                hr[o] = (bf16_t)fmaxf(hn, 0.f);
            }
        }
    } else {
        const int crow0 = brow + wr * 64 + ((l >> 4) << 2);
        const int ccol0 = bcol + wc * 64 + (l & 15);
#pragma unroll
        for (int m = 0; m < 4; ++m) {
#pragma unroll
            for (int n = 0; n < 4; ++n) {
                const int col = ccol0 + n * 16;
                const float badd = bias ? bias[col] : 0.0f;
#pragma unroll
                for (int j = 0; j < 4; ++j) {
                    const int row = crow0 + m * 16 + j;
                    C[(size_t)row * N + col] = acc[m][n][j] + badd;
                }
            }
        }
    }
}

// ---------------- launch ----------------

extern "C" void kernel_launch(void* const* d_in, const int* in_sizes, int n_in,
                              void* d_out, int out_size, void* d_ws, size_t ws_size,
                              hipStream_t stream)
{
    const float* hidden = (const float*)d_in[0];
    const float* Wih = (const float*)d_in[1];
    const float* Whh = (const float*)d_in[2];
    const float* bih = (const float*)d_in[3];
    const float* bhh = (const float*)d_in[4];
    const float* Wout = (const float*)d_in[5];
    const float* bout = (const float*)d_in[6];
    float* out = (float*)d_out;
    (void)in_sizes; (void)n_in; (void)out_size;

    char* ws = (char*)d_ws;
    size_t off = 0;
    bf16_t* Wc0 = (bf16_t*)(ws + off); off += (size_t)K4 * H_DIM * 2;        // 8 MB
    bf16_t* Wc  = (bf16_t*)(ws + off); off += (size_t)K4 * H_DIM * 2;        // 8 MB
    bf16_t* Wob = (bf16_t*)(ws + off); off += (size_t)H_DIM * H_DIM * 2;     // 2 MB
    float*  biasc = (float*)(ws + off); off += (size_t)K4 * 4;               // 16 KB
    bf16_t* hbA = (bf16_t*)(ws + off); off += (size_t)BATCH_N * H_DIM * 2;   // 8 MB
    bf16_t* hbB = (bf16_t*)(ws + off); off += (size_t)BATCH_N * H_DIM * 2;   // 8 MB

    const size_t hr_step = (size_t)BATCH_N * H_DIM;
    const size_t need_batched = off + NSTEPS * hr_step * 2;
    const bool batched = (ws_size >= need_batched);
    bf16_t* hr_all = (bf16_t*)(ws + off);               // 128 MB if batched

    prep_weights<<<1024, 256, 0, stream>>>(Wih, Whh, bih, bhh, Wout, Wc0, Wc, Wob, biasc);
    prep_h<<<2048, 256, 0, stream>>>(hidden, hbA);

    for (int t = 0; t < NSTEPS; ++t) {
        bf16_t* hin  = (t & 1) ? hbB : hbA;
        bf16_t* hout = (t & 1) ? hbA : hbB;
        bf16_t* hr_t = batched ? (hr_all + (size_t)t * hr_step) : hr_all;
        // fused gate GEMM: M=4096, N=4096, K=1024 + GRU epilogue
        gemm_bt<true><<<dim3(K4 / 128, BATCH_N / 128), 256, 0, stream>>>(
            hin, (t == 0) ? Wc0 : Wc, BATCH_N, K4, H_DIM,
            nullptr, nullptr, biasc, hout, hr_t);
        if (!batched) {
            gemm_bt<false><<<dim3(H_DIM / 128, BATCH_N / 128), 256, 0, stream>>>(
                hr_t, Wob, BATCH_N, H_DIM, H_DIM,
                out + (size_t)t * hr_step, bout, nullptr, nullptr, nullptr);
        }
    }
    if (batched) {
        // one big out GEMM: M = 16*4096, N = 1024, K = 1024
        gemm_bt<false><<<dim3(H_DIM / 128, (NSTEPS * BATCH_N) / 128), 256, 0, stream>>>(
            hr_all, Wob, NSTEPS * BATCH_N, H_DIM, H_DIM,
            out, bout, nullptr, nullptr, nullptr);
    }
}

// Round 4
// 825.334 us; speedup vs baseline: 1.3426x; 1.3426x over previous
//
#include <hip/hip_runtime.h>
#include <hip/hip_bf16.h>

// GRU, 16 steps, B=4096, H=1024. x==h for steps>=1 -> combined gate weights.
// Gate GEMM (fused): Z = h_bf16 @ Wc'[4H,H]^T, gate-interleaved; GRU epilogue
//   in-register. Out GEMM batched over all 16 steps.
// GEMM core: 256x256 tile, BK=32, 8 waves, 4-deep LDS pipeline with counted
//   vmcnt (never 0 in steady state), raw s_barrier, setprio around MFMA,
//   both-sides XOR swizzle (conflict-free ds_read_b128).

#define H_DIM 1024
#define BATCH_N 4096
#define NSTEPS 16
#define K4 (4 * H_DIM)

typedef __bf16 bf16_t;
typedef __bf16 bf16x8 __attribute__((ext_vector_type(8)));
typedef float f32x4 __attribute__((ext_vector_type(4)));

__device__ __forceinline__ float sigm(float x) { return 1.0f / (1.0f + __expf(-x)); }

// ---------------- prep kernels ----------------
// Wc' row c' (0..4095): gate g=(c'>>4)&3, h-row hc=((c'>>6)<<4)|(c'&15)
//   g: 0=r (Wih+Whh), 1=z (Wih+Whh), 2=i_n (Wih), 3=h_n (Whh)

__global__ __launch_bounds__(256) void prep_weights(
    const float* __restrict__ Wih, const float* __restrict__ Whh,
    const float* __restrict__ bih, const float* __restrict__ bhh,
    const float* __restrict__ Wout,
    bf16_t* __restrict__ Wc0, bf16_t* __restrict__ Wc,
    bf16_t* __restrict__ Wob, float* __restrict__ biasc)
{
    const int stride = gridDim.x * blockDim.x;
    const int idx = blockIdx.x * blockDim.x + threadIdx.x;

    const int total = K4 * H_DIM;
    for (int i = idx; i < total; i += stride) {
        const int c2 = i >> 10;            // permuted row
        const int col = i & (H_DIM - 1);
        const int gate = (c2 >> 4) & 3;
        const int hc = ((c2 >> 6) << 4) | (c2 & 15);
        float vc, v0;
        if (gate == 0) {
            float a = Wih[(size_t)hc * H_DIM + col];
            float b = Whh[(size_t)hc * H_DIM + col];
            vc = a + b; v0 = b;
        } else if (gate == 1) {
            float a = Wih[(size_t)(H_DIM + hc) * H_DIM + col];
            float b = Whh[(size_t)(H_DIM + hc) * H_DIM + col];
            vc = a + b; v0 = b;
        } else if (gate == 2) {
            vc = Wih[(size_t)(2 * H_DIM + hc) * H_DIM + col];
            v0 = 0.0f;   // step 0: x = 0
        } else {
            float b = Whh[(size_t)(2 * H_DIM + hc) * H_DIM + col];
            vc = b; v0 = b;
        }
        Wc[i]  = (bf16_t)vc;
        Wc0[i] = (bf16_t)v0;
    }
    for (int i = idx; i < H_DIM * H_DIM; i += stride)
        Wob[i] = (bf16_t)Wout[i];
    // biasc gate-major [4][H]
    for (int i = idx; i < K4; i += stride) {
        const int gate = i >> 10;
        const int hc = i & (H_DIM - 1);
        float v;
        if (gate == 0)      v = bih[hc] + bhh[hc];
        else if (gate == 1) v = bih[H_DIM + hc] + bhh[H_DIM + hc];
        else if (gate == 2) v = bih[2 * H_DIM + hc];
        else                v = bhh[2 * H_DIM + hc];
        biasc[i] = v;
    }
}

__global__ __launch_bounds__(256) void prep_h(
    const float* __restrict__ h0, bf16_t* __restrict__ hb)
{
    const int stride = gridDim.x * blockDim.x;
    for (int i = blockIdx.x * blockDim.x + threadIdx.x; i < BATCH_N * H_DIM; i += stride)
        hb[i] = (bf16_t)h0[i];
}

// ---------------- 256x256 deep-pipelined GEMM ----------------
// C[M,N] = A[M,K] @ Bm[N,K]^T. 8 waves: wr=w>>2 (2), wc=w&3 (4).
// Wave output 128x64. acc[8][4]. BK=32, 4 LDS buffers each (A,B):
//   A: lds[0      + buf*8192 + row*32 + col], row in [0,256), col in [0,32)
//   B: lds[32768  + buf*8192 + row*32 + col]
// Swizzle (involution, elem units): LDS[row][c] = G[row][c ^ (((row>>1)&3)<<3)]
//   staging: linear LDS dest, pre-swizzled global source col
//   ds_read: col = ((l>>4)<<3) ^ (((l>>1)&3)<<3)  -> conflict-free

__device__ __forceinline__ void stage_half(
    const bf16_t* __restrict__ g, int grow0, int K, int k0,
    bf16_t* ldsbase, int l)
{
    const int colsrc = (((l & 3) ^ ((l >> 3) & 3)) << 3);
    const bf16_t* ga = g + (size_t)(grow0 + (l >> 2)) * K + k0 + colsrc;
    __builtin_amdgcn_global_load_lds(
        (const __attribute__((address_space(1))) void*)ga,
        (__attribute__((address_space(3))) void*)ldsbase, 16, 0, 0);
}

template <bool FUSED>
__global__ __launch_bounds__(512, 2) void gemm256(
    const bf16_t* __restrict__ A, const bf16_t* __restrict__ Bm,
    int M, int N, int K,
    float* __restrict__ C, const float* __restrict__ bias,
    const float* __restrict__ biasc,
    bf16_t* __restrict__ hbout, bf16_t* __restrict__ hr)
{
    __shared__ bf16_t lds[65536];   // 128 KiB

    const int tid = threadIdx.x;
    const int l = tid & 63;
    const int w = tid >> 6;         // 0..7
    const int wr = w >> 2;          // 0..1
    const int wc = w & 3;           // 0..3

    // block swizzle
    int bx, by;
    if constexpr (FUSED) {
        // 16x16 grid -> 8 XCD regions of 4(bx) x 8(by)
        const int d = blockIdx.x;
        const int r = d & 7, s = d >> 3;
        bx = (r & 3) * 4 + (s & 3);
        by = (r >> 2) * 8 + (s >> 2);
    } else {
        const int nbx = N >> 8;
        const int cpx = gridDim.x >> 3;
        const int d = blockIdx.x;
        const int bid = (d & 7) * cpx + (d >> 3);
        bx = bid % nbx;
        by = bid / nbx;
    }
    const int brow = by * 256;
    const int bcol = bx * 256;

    bf16_t* ldsA = lds;
    bf16_t* ldsB = lds + 32768;

    f32x4 acc[8][4];
    const f32x4 zero = {0.f, 0.f, 0.f, 0.f};
#pragma unroll
    for (int m = 0; m < 8; ++m)
#pragma unroll
        for (int n = 0; n < 4; ++n) acc[m][n] = zero;

    const int nk = K >> 5;   // BK=32

#define STAGE_A(u, half)  stage_half(A,  brow + (half) * 128 + w * 16, K, (u) * 32, \
        ldsA + ((u) & 3) * 8192 + ((half) * 128 + w * 16) * 32, l)
#define STAGE_B(u, half)  stage_half(Bm, bcol + (half) * 128 + w * 16, K, (u) * 32, \
        ldsB + ((u) & 3) * 8192 + ((half) * 128 + w * 16) * 32, l)

    // prologue: stage tiles 0,1,2
    for (int u = 0; u < 3 && u < nk; ++u) {
        STAGE_A(u, 0); STAGE_A(u, 1);
        STAGE_B(u, 0); STAGE_B(u, 1);
    }

    const int colrd = (((l >> 4) ^ ((l >> 1) & 3)) << 3);
    const int ar0 = (wr * 128 + (l & 15)) * 32 + colrd;
    const int br0 = (wc * 64 + (l & 15)) * 32 + colrd;

    for (int t = 0; t < nk; ++t) {
        const int rem = nk - 1 - t;
        if (rem >= 2)      asm volatile("s_waitcnt vmcnt(8)" ::: "memory");
        else if (rem == 1) asm volatile("s_waitcnt vmcnt(4)" ::: "memory");
        else               asm volatile("s_waitcnt vmcnt(0)" ::: "memory");
        __builtin_amdgcn_s_barrier();

        const int pu = t + 3;
        const int ab = (t & 3) * 8192;
        bf16x8 bfrag[4], afrag[4];

        // ---- phase 0: stage A(t+3), read B + A[m0-3], MFMA quadrant 0 ----
        if (pu < nk) { STAGE_A(pu, 0); STAGE_A(pu, 1); }
#pragma unroll
        for (int n = 0; n < 4; ++n)
            bfrag[n] = *(const bf16x8*)&ldsB[ab + br0 + n * 512];
#pragma unroll
        for (int m = 0; m < 4; ++m)
            afrag[m] = *(const bf16x8*)&ldsA[ab + ar0 + m * 512];
        __builtin_amdgcn_s_setprio(1);
#pragma unroll
        for (int m = 0; m < 4; ++m)
#pragma unroll
            for (int n = 0; n < 4; ++n)
                acc[m][n] = __builtin_amdgcn_mfma_f32_16x16x32_bf16(afrag[m], bfrag[n], acc[m][n], 0, 0, 0);
        __builtin_amdgcn_s_setprio(0);
        __builtin_amdgcn_s_barrier();

        // ---- phase 1: stage B(t+3), read A[m4-7], MFMA quadrant 1 ----
        if (pu < nk) { STAGE_B(pu, 0); STAGE_B(pu, 1); }
#pragma unroll
        for (int m = 0; m < 4; ++m)
            afrag[m] = *(const bf16x8*)&ldsA[ab + ar0 + (m + 4) * 512];
        __builtin_amdgcn_s_setprio(1);
#pragma unroll
        for (int m = 0; m < 4; ++m)
#pragma unroll
            for (int n = 0; n < 4; ++n)
                acc[m + 4][n] = __builtin_amdgcn_mfma_f32_16x16x32_bf16(afrag[m], bfrag[n], acc[m + 4][n], 0, 0, 0);
        __builtin_amdgcn_s_setprio(0);
    }
#undef STAGE_A
#undef STAGE_B

    // C/D layout: col = lane&15, row = (lane>>4)*4 + j  [verified m89/m91]
    if constexpr (FUSED) {
        // fragment n = gate n of h-col hc
        const int hc = (bx * 4 + wc) * 16 + (l & 15);
        const float br_ = biasc[hc];
        const float bz_ = biasc[H_DIM + hc];
        const float bi_ = biasc[2 * H_DIM + hc];
        const float bh_ = biasc[3 * H_DIM + hc];
        const int r0 = brow + wr * 128 + ((l >> 4) << 2);
#pragma unroll
        for (int m = 0; m < 8; ++m) {
#pragma unroll
            for (int j = 0; j < 4; ++j) {
                const int row = r0 + m * 16 + j;
                const size_t o = (size_t)row * H_DIM + hc;
                const float hold = (float)A[o];   // h_old (read-only this launch)
                const float r = sigm(acc[m][0][j] + br_);
                const float z = sigm(acc[m][1][j] + bz_);
                float a = acc[m][2][j] + bi_ + r * (acc[m][3][j] + bh_);
                a = fminf(fmaxf(a, -30.f), 30.f);
                const float e = __expf(-2.f * a);
                const float nn = (1.f - e) / (1.f + e);
                const float hn = (1.f - z) * nn + z * hold;
                hbout[o] = (bf16_t)hn;
                hr[o] = (bf16_t)fmaxf(hn, 0.f);
            }
        }
    } else {
        const int r0 = brow + wr * 128 + ((l >> 4) << 2);
        const int c0 = bcol + wc * 64 + (l & 15);
#pragma unroll
        for (int m = 0; m < 8; ++m) {
#pragma unroll
            for (int n = 0; n < 4; ++n) {
                const int col = c0 + n * 16;
                const float badd = bias ? bias[col] : 0.0f;
#pragma unroll
                for (int j = 0; j < 4; ++j) {
                    const int row = r0 + m * 16 + j;
                    C[(size_t)row * N + col] = acc[m][n][j] + badd;
                }
            }
        }
    }
}

// ---------------- launch ----------------

extern "C" void kernel_launch(void* const* d_in, const int* in_sizes, int n_in,
                              void* d_out, int out_size, void* d_ws, size_t ws_size,
                              hipStream_t stream)
{
    const float* hidden = (const float*)d_in[0];
    const float* Wih = (const float*)d_in[1];
    const float* Whh = (const float*)d_in[2];
    const float* bih = (const float*)d_in[3];
    const float* bhh = (const float*)d_in[4];
    const float* Wout = (const float*)d_in[5];
    const float* bout = (const float*)d_in[6];
    float* out = (float*)d_out;
    (void)in_sizes; (void)n_in; (void)out_size;

    char* ws = (char*)d_ws;
    size_t off = 0;
    bf16_t* Wc0 = (bf16_t*)(ws + off); off += (size_t)K4 * H_DIM * 2;        // 8 MB
    bf16_t* Wc  = (bf16_t*)(ws + off); off += (size_t)K4 * H_DIM * 2;        // 8 MB
    bf16_t* Wob = (bf16_t*)(ws + off); off += (size_t)H_DIM * H_DIM * 2;     // 2 MB
    float*  biasc = (float*)(ws + off); off += (size_t)K4 * 4;               // 16 KB
    bf16_t* hbA = (bf16_t*)(ws + off); off += (size_t)BATCH_N * H_DIM * 2;   // 8 MB
    bf16_t* hbB = (bf16_t*)(ws + off); off += (size_t)BATCH_N * H_DIM * 2;   // 8 MB

    const size_t hr_step = (size_t)BATCH_N * H_DIM;
    const size_t need_batched = off + NSTEPS * hr_step * 2;
    const bool batched = (ws_size >= need_batched);
    bf16_t* hr_all = (bf16_t*)(ws + off);               // 128 MB if batched

    prep_weights<<<1024, 256, 0, stream>>>(Wih, Whh, bih, bhh, Wout, Wc0, Wc, Wob, biasc);
    prep_h<<<2048, 256, 0, stream>>>(hidden, hbA);

    for (int t = 0; t < NSTEPS; ++t) {
        bf16_t* hin  = (t & 1) ? hbB : hbA;
        bf16_t* hout = (t & 1) ? hbA : hbB;
        bf16_t* hr_t = batched ? (hr_all + (size_t)t * hr_step) : hr_all;
        // fused gate GEMM: M=4096, N=4096, K=1024 + GRU epilogue (16x16 grid)
        gemm256<true><<<(BATCH_N / 256) * (K4 / 256), 512, 0, stream>>>(
            hin, (t == 0) ? Wc0 : Wc, BATCH_N, K4, H_DIM,
            nullptr, nullptr, biasc, hout, hr_t);
        if (!batched) {
            gemm256<false><<<(BATCH_N / 256) * (H_DIM / 256), 512, 0, stream>>>(
                hr_t, Wob, BATCH_N, H_DIM, H_DIM,
                out + (size_t)t * hr_step, bout, nullptr, nullptr, nullptr);
        }
    }
    if (batched) {
        // one big out GEMM: M = 16*4096, N = 1024, K = 1024
        gemm256<false><<<((NSTEPS * BATCH_N) / 256) * (H_DIM / 256), 512, 0, stream>>>(
            hr_all, Wob, NSTEPS * BATCH_N, H_DIM, H_DIM,
            out, bout, nullptr, nullptr, nullptr);
    }
}